// Round 1
// baseline (400.676 us; speedup 1.0000x reference)
//
#include <hip/hip_runtime.h>

#define NQ 4096
#define NS 8192
#define DD 256
#define NC 64
#define INFV 1000.0f

typedef __attribute__((ext_vector_type(8))) __bf16 bf16x8;
typedef __attribute__((ext_vector_type(4))) float floatx4;
typedef __attribute__((ext_vector_type(4))) unsigned int uint4v;

__device__ inline unsigned short f2bf(float f) {
    unsigned int u = __builtin_bit_cast(unsigned int, f);
    unsigned int r = (u + 0x7FFFu + ((u >> 16) & 1u)) >> 16;
    return (unsigned short)r;
}

// ---------------- K1a: convert to bf16 + row squared norms ----------------
__global__ __launch_bounds__(256) void k_prep(const float* __restrict__ xq,
                                              const float* __restrict__ xs,
                                              unsigned short* __restrict__ xqh,
                                              unsigned short* __restrict__ xsh,
                                              float* __restrict__ nq2,
                                              float* __restrict__ ns2) {
    int row = blockIdx.x * 4 + (threadIdx.x >> 6);
    int lane = threadIdx.x & 63;
    const float* src;
    unsigned short* dst;
    float* nrm;
    if (row < NQ) {
        src = xq + (size_t)row * DD; dst = xqh + (size_t)row * DD; nrm = nq2 + row;
    } else {
        int r = row - NQ;
        src = xs + (size_t)r * DD; dst = xsh + (size_t)r * DD; nrm = ns2 + r;
    }
    float4 v = ((const float4*)src)[lane];
    float s = v.x * v.x + v.y * v.y + v.z * v.z + v.w * v.w;
    ushort4 u4 = make_ushort4(f2bf(v.x), f2bf(v.y), f2bf(v.z), f2bf(v.w));
    ((ushort4*)dst)[lane] = u4;
#pragma unroll
    for (int off = 32; off; off >>= 1) s += __shfl_xor(s, off, 64);
    if (lane == 0) *nrm = s;
}

// ---------------- K1b: class counts ----------------
__global__ void k_count(const int* __restrict__ ys, int* __restrict__ counts,
                        int* __restrict__ qcounts) {
    int j = blockIdx.x * 256 + threadIdx.x;
    if (j < NS) {
        int c = ys[j];
        atomicAdd(&counts[c], 1);
        if (j < NQ) atomicAdd(&qcounts[c], 1);
    }
}

// ---------------- K1c: exclusive scan (tiny, serial) ----------------
__global__ void k_scan(const int* __restrict__ counts, const int* __restrict__ qcounts,
                       int* __restrict__ soff, int* __restrict__ qoff) {
    if (threadIdx.x == 0) {
        int a = 0, b = 0;
        for (int i = 0; i < NC; ++i) {
            soff[i] = a; a += counts[i];
            qoff[i] = b; b += qcounts[i];
        }
    }
}

// ---------------- K1d: scatter into class buckets ----------------
__global__ void k_scatter(const int* __restrict__ ys, const int* __restrict__ soff,
                          const int* __restrict__ qoff, int* __restrict__ scur,
                          int* __restrict__ qcur, int* __restrict__ sperm,
                          int* __restrict__ qperm) {
    int j = blockIdx.x * 256 + threadIdx.x;
    if (j < NS) {
        int c = ys[j];
        int p = atomicAdd(&scur[c], 1);
        sperm[soff[c] + p] = j;
        if (j < NQ) {
            int q = atomicAdd(&qcur[c], 1);
            qperm[qoff[c] + q] = j;
        }
    }
}

// ---------------- K2: main GEMM -> per-class sums ----------------
// block tile: 64 rows x 128 cols per j-tile, K=256 staged in two 128-halves.
// 4 waves in 2x2: each wave 32 rows x 64 cols (2x4 MFMA 16x16x32 tiles).
__global__ __launch_bounds__(256) void k_main(const unsigned short* __restrict__ xqh,
                                              const unsigned short* __restrict__ xsh,
                                              const float* __restrict__ nq2,
                                              const float* __restrict__ ns2,
                                              const int* __restrict__ ys,
                                              float* __restrict__ summed) {
    __shared__ unsigned short Bsh[128 * 136];  // 128 rows x (128 elems + 8 pad)
    __shared__ float csum[64 * 64];
    __shared__ float ns2sh[128];
    __shared__ int clssh[128];

    const int tid = threadIdx.x;
    const int lane = tid & 63;
    const int wave = tid >> 6;
    const int quad = lane >> 4;
    const int l15 = lane & 15;
    const int rowW = wave >> 1;  // 0..1
    const int colW = wave & 1;   // 0..1
    const int row0 = blockIdx.y * 64;
    const int j0s = blockIdx.x * 1024;

    for (int i = tid; i < 4096; i += 256) csum[i] = 0.0f;

    // A fragments: rows rowW*32 + m*16 + l15, k = kk*32 + quad*8 .. +7
    bf16x8 afr[2][8];
#pragma unroll
    for (int m = 0; m < 2; ++m) {
        int gr = row0 + rowW * 32 + m * 16 + l15;
        const unsigned short* ap = xqh + (size_t)gr * DD + quad * 8;
#pragma unroll
        for (int kk = 0; kk < 8; ++kk) afr[m][kk] = *(const bf16x8*)(ap + kk * 32);
    }
    float nqr[2][4];
#pragma unroll
    for (int m = 0; m < 2; ++m)
#pragma unroll
        for (int r = 0; r < 4; ++r)
            nqr[m][r] = nq2[row0 + rowW * 32 + m * 16 + quad * 4 + r];

    floatx4 acc[2][4];
#pragma unroll
    for (int m = 0; m < 2; ++m)
#pragma unroll
        for (int n = 0; n < 4; ++n) acc[m][n] = (floatx4)0.0f;

    for (int jt = 0; jt < 8; ++jt) {
        const int j0 = j0s + jt * 128;
#pragma unroll
        for (int kh = 0; kh < 2; ++kh) {
            __syncthreads();
            if (kh == 0 && tid < 128) {
                ns2sh[tid] = ns2[j0 + tid];
                clssh[tid] = ys[j0 + tid];
            }
            const unsigned short* gbase = xsh + (size_t)j0 * DD + kh * 128;
#pragma unroll
            for (int it = 0; it < 8; ++it) {
                int ch = it * 256 + tid;
                int row = ch >> 4, u = ch & 15;
                *(uint4v*)(&Bsh[row * 136 + u * 8]) =
                    *(const uint4v*)(gbase + row * 256 + u * 8);
            }
            __syncthreads();
#pragma unroll
            for (int k = 0; k < 4; ++k) {
                bf16x8 bfr[4];
#pragma unroll
                for (int n = 0; n < 4; ++n) {
                    int colc = colW * 64 + n * 16 + l15;
                    bfr[n] = *(const bf16x8*)(&Bsh[colc * 136 + k * 32 + quad * 8]);
                }
#pragma unroll
                for (int m = 0; m < 2; ++m)
#pragma unroll
                    for (int n = 0; n < 4; ++n)
                        acc[m][n] = __builtin_amdgcn_mfma_f32_16x16x32_bf16(
                            afr[m][kh * 4 + k], bfr[n], acc[m][n], 0, 0, 0);
            }
        }
        // epilogue: logits -> per-class sums (diagonal contributes 0; fixed in k_final)
#pragma unroll
        for (int n = 0; n < 4; ++n) {
            int colc = colW * 64 + n * 16 + l15;
            int gcol = j0 + colc;
            float nsc = ns2sh[colc];
            int cls = clssh[colc];
#pragma unroll
            for (int m = 0; m < 2; ++m) {
                int rbase = rowW * 32 + m * 16 + quad * 4;
#pragma unroll
                for (int r = 0; r < 4; ++r) {
                    float logit = fminf(acc[m][n][r] - 0.5f * (nqr[m][r] + nsc), 0.0f);
                    if (gcol == row0 + rbase + r) logit = 0.0f;
                    atomicAdd(&csum[(rbase + r) * 64 + cls], logit);
                }
                acc[m][n] = (floatx4)0.0f;
            }
        }
    }
    __syncthreads();
    for (int i = tid; i < 4096; i += 256)
        atomicAdd(&summed[(size_t)(row0 + (i >> 6)) * 64 + (i & 63)], csum[i]);
}

// ---------------- K3: positive logsumexp per query (per-class GEMM) ----------------
__global__ __launch_bounds__(256) void k_pos(const unsigned short* __restrict__ xqh,
                                             const unsigned short* __restrict__ xsh,
                                             const float* __restrict__ nq2,
                                             const float* __restrict__ ns2,
                                             const int* __restrict__ counts,
                                             const int* __restrict__ qcounts,
                                             const int* __restrict__ soff,
                                             const int* __restrict__ qoff,
                                             const int* __restrict__ sperm,
                                             const int* __restrict__ qperm,
                                             float* __restrict__ poslog) {
    __shared__ __align__(16) char sbuf[34816];  // union: Bsh (128x136 ushort) / Lt (64x132 f32)
    __shared__ int spsh[128];
    __shared__ float ns2sh[128];
    __shared__ int qlsh[64];
    __shared__ float nq2sh[64];

    unsigned short* Bsh = (unsigned short*)sbuf;
    float* Lt = (float*)sbuf;

    const int c = blockIdx.x;
    const int mc = counts[c];
    const int qc = qcounts[c];
    if (qc == 0) return;
    const int sbase = soff[c];
    const int qbase = qoff[c];
    const float ov = (mc > 1) ? -INFV : 0.0f;

    const int tid = threadIdx.x;
    const int lane = tid & 63;
    const int wave = tid >> 6;
    const int quad = lane >> 4;
    const int l15 = lane & 15;
    const int rowW = wave >> 1;
    const int colW = wave & 1;

    for (int q0 = 0; q0 < qc; q0 += 64) {
        __syncthreads();
        if (tid < 64) {
            int idx = q0 + tid;
            int qi = (idx < qc) ? qperm[qbase + idx] : -1;
            qlsh[tid] = qi;
            nq2sh[tid] = (qi >= 0) ? nq2[qi] : 0.0f;
        }
        __syncthreads();

        bf16x8 afr[2][8];
#pragma unroll
        for (int m = 0; m < 2; ++m) {
            int rl = rowW * 32 + m * 16 + l15;
            int qi = qlsh[rl];
            int qiL = qi < 0 ? 0 : qi;
            const unsigned short* ap = xqh + (size_t)qiL * DD + quad * 8;
#pragma unroll
            for (int kk = 0; kk < 8; ++kk) afr[m][kk] = *(const bf16x8*)(ap + kk * 32);
        }
        float nqr[2][4];
        int qid[2][4];
#pragma unroll
        for (int m = 0; m < 2; ++m)
#pragma unroll
            for (int r = 0; r < 4; ++r) {
                int rl = rowW * 32 + m * 16 + quad * 4 + r;
                qid[m][r] = qlsh[rl];
                nqr[m][r] = nq2sh[rl];
            }

        float mrun[16], srun[16];
#pragma unroll
        for (int i = 0; i < 16; ++i) { mrun[i] = -1e30f; srun[i] = 0.0f; }

        floatx4 acc[2][4];
#pragma unroll
        for (int m = 0; m < 2; ++m)
#pragma unroll
            for (int n = 0; n < 4; ++n) acc[m][n] = (floatx4)0.0f;

        for (int j0 = 0; j0 < mc; j0 += 128) {
            __syncthreads();
            if (tid < 128) {
                int idx = j0 + tid;
                int sj = (idx < mc) ? sperm[sbase + idx] : -1;
                spsh[tid] = sj;
                ns2sh[tid] = (sj >= 0) ? ns2[sj] : 0.0f;
            }
            __syncthreads();
#pragma unroll
            for (int kh = 0; kh < 2; ++kh) {
#pragma unroll
                for (int it = 0; it < 8; ++it) {
                    int ch = it * 256 + tid;
                    int row = ch >> 4, u = ch & 15;
                    int sj = spsh[row];
                    int sjL = sj < 0 ? 0 : sj;
                    *(uint4v*)(&Bsh[row * 136 + u * 8]) =
                        *(const uint4v*)(xsh + (size_t)sjL * DD + kh * 128 + u * 8);
                }
                __syncthreads();
#pragma unroll
                for (int k = 0; k < 4; ++k) {
                    bf16x8 bfr[4];
#pragma unroll
                    for (int n = 0; n < 4; ++n) {
                        int colc = colW * 64 + n * 16 + l15;
                        bfr[n] = *(const bf16x8*)(&Bsh[colc * 136 + k * 32 + quad * 8]);
                    }
#pragma unroll
                    for (int m = 0; m < 2; ++m)
#pragma unroll
                        for (int n = 0; n < 4; ++n)
                            acc[m][n] = __builtin_amdgcn_mfma_f32_16x16x32_bf16(
                                afr[m][kh * 4 + k], bfr[n], acc[m][n], 0, 0, 0);
                }
                __syncthreads();
            }
            // write logits to Lt (reuses Bsh memory; safe after sync)
#pragma unroll
            for (int n = 0; n < 4; ++n) {
                int colc = colW * 64 + n * 16 + l15;
                bool cval = (j0 + colc) < mc;
                int sj = spsh[colc];
                float nsc = ns2sh[colc];
#pragma unroll
                for (int m = 0; m < 2; ++m) {
                    int rbase = rowW * 32 + m * 16 + quad * 4;
#pragma unroll
                    for (int r = 0; r < 4; ++r) {
                        float logit = fminf(acc[m][n][r] - 0.5f * (nqr[m][r] + nsc), 0.0f);
                        if (sj == qid[m][r]) logit = ov;  // diagonal override
                        if (!cval) logit = -1e30f;
                        Lt[(rbase + r) * 132 + colc] = logit;
                    }
                    acc[m][n] = (floatx4)0.0f;
                }
            }
            __syncthreads();
            // per-row online merge; wave owns rows wave*16..+15
#pragma unroll
            for (int rr = 0; rr < 16; ++rr) {
                int rl = wave * 16 + rr;
                float v0 = Lt[rl * 132 + lane];
                float v1 = Lt[rl * 132 + 64 + lane];
                float mt = fmaxf(v0, v1);
#pragma unroll
                for (int off = 32; off; off >>= 1) mt = fmaxf(mt, __shfl_xor(mt, off, 64));
                float e = __expf(v0 - mt) + __expf(v1 - mt);
#pragma unroll
                for (int off = 32; off; off >>= 1) e += __shfl_xor(e, off, 64);
                float mn = fmaxf(mrun[rr], mt);
                srun[rr] = srun[rr] * __expf(mrun[rr] - mn) + e * __expf(mt - mn);
                mrun[rr] = mn;
            }
        }
#pragma unroll
        for (int rr = 0; rr < 16; ++rr) {
            int rl = wave * 16 + rr;
            int qi = qlsh[rl];
            if (qi >= 0 && lane == 0) poslog[qi] = mrun[rr] + __logf(srun[rr]);
        }
    }
}

// ---------------- K4: finalize ----------------
__global__ __launch_bounds__(256) void k_final(const float* __restrict__ summed,
                                               const int* __restrict__ counts,
                                               const int* __restrict__ yq,
                                               const float* __restrict__ poslog,
                                               float* __restrict__ out) {
    int row = blockIdx.x * 4 + (threadIdx.x >> 6);
    int lane = threadIdx.x & 63;
    int cnt = counts[lane];
    int y = yq[row];
    float s = summed[(size_t)row * 64 + lane];
    if (lane == y && cnt > 1) s += -INFV;  // diagonal override (k_main contributed 0)
    float adj = (float)(cnt - (lane == y ? 1 : 0));
    float v = s / adj;
    float m = v;
#pragma unroll
    for (int off = 32; off; off >>= 1) m = fmaxf(m, __shfl_xor(m, off, 64));
    float e = __expf(v - m);
#pragma unroll
    for (int off = 32; off; off >>= 1) e += __shfl_xor(e, off, 64);
    if (lane == 0) {
        float neg = m + __logf(e);
        atomicAdd(out, (neg - poslog[row]) * (1.0f / (float)NQ));
    }
}

extern "C" void kernel_launch(void* const* d_in, const int* in_sizes, int n_in,
                              void* d_out, int out_size, void* d_ws, size_t ws_size,
                              hipStream_t stream) {
    const float* xq = (const float*)d_in[0];
    const int* yq = (const int*)d_in[1];
    const float* xs = (const float*)d_in[2];
    const int* ys = (const int*)d_in[3];
    float* out = (float*)d_out;
    char* ws = (char*)d_ws;

    unsigned short* xqh = (unsigned short*)(ws + 0);        // 2 MB
    unsigned short* xsh = (unsigned short*)(ws + 2097152);  // 4 MB
    float* nq2 = (float*)(ws + 6291456);
    float* ns2 = (float*)(ws + 6307840);
    int* counts = (int*)(ws + 6340608);
    int* qcounts = (int*)(ws + 6340864);
    int* soff = (int*)(ws + 6341120);
    int* qoff = (int*)(ws + 6341376);
    int* scur = (int*)(ws + 6341632);
    int* qcur = (int*)(ws + 6341888);
    int* sperm = (int*)(ws + 6342144);
    int* qperm = (int*)(ws + 6374912);
    float* summed = (float*)(ws + 6391296);  // 1 MB
    float* poslog = (float*)(ws + 7439872);

    // zero: counts..summed (incl. cursors/perms) + d_out (ws/d_out are poisoned 0xAA)
    hipMemsetAsync(ws + 6340608, 0, 1099264, stream);
    hipMemsetAsync(d_out, 0, (size_t)out_size * 4, stream);

    k_prep<<<dim3((NQ + NS) / 4), dim3(256), 0, stream>>>(xq, xs, xqh, xsh, nq2, ns2);
    k_count<<<dim3(NS / 256), dim3(256), 0, stream>>>(ys, counts, qcounts);
    k_scan<<<dim3(1), dim3(64), 0, stream>>>(counts, qcounts, soff, qoff);
    k_scatter<<<dim3(NS / 256), dim3(256), 0, stream>>>(ys, soff, qoff, scur, qcur,
                                                        sperm, qperm);
    k_main<<<dim3(8, 64), dim3(256), 0, stream>>>(xqh, xsh, nq2, ns2, ys, summed);
    k_pos<<<dim3(NC), dim3(256), 0, stream>>>(xqh, xsh, nq2, ns2, counts, qcounts, soff,
                                              qoff, sperm, qperm, poslog);
    k_final<<<dim3(NQ / 4), dim3(256), 0, stream>>>(summed, counts, yq, poslog, out);
}

// Round 2
// 220.020 us; speedup vs baseline: 1.8211x; 1.8211x over previous
//
#include <hip/hip_runtime.h>

#define NQ 4096
#define NS 8192
#define DD 256
#define NC 64
#define INFV 1000.0f

typedef __attribute__((ext_vector_type(8))) __bf16 bf16x8;
typedef __attribute__((ext_vector_type(4))) float floatx4;
typedef __attribute__((ext_vector_type(4))) unsigned int uint4v;

__device__ inline unsigned short f2bf(float f) {
    unsigned int u = __builtin_bit_cast(unsigned int, f);
    unsigned int r = (u + 0x7FFFu + ((u >> 16) & 1u)) >> 16;
    return (unsigned short)r;
}

// ---------------- K1a: convert to bf16 + row squared norms ----------------
__global__ __launch_bounds__(256) void k_prep(const float* __restrict__ xq,
                                              const float* __restrict__ xs,
                                              unsigned short* __restrict__ xqh,
                                              unsigned short* __restrict__ xsh,
                                              float* __restrict__ nq2,
                                              float* __restrict__ ns2) {
    int row = blockIdx.x * 4 + (threadIdx.x >> 6);
    int lane = threadIdx.x & 63;
    const float* src;
    unsigned short* dst;
    float* nrm;
    if (row < NQ) {
        src = xq + (size_t)row * DD; dst = xqh + (size_t)row * DD; nrm = nq2 + row;
    } else {
        int r = row - NQ;
        src = xs + (size_t)r * DD; dst = xsh + (size_t)r * DD; nrm = ns2 + r;
    }
    float4 v = ((const float4*)src)[lane];
    float s = v.x * v.x + v.y * v.y + v.z * v.z + v.w * v.w;
    ushort4 u4 = make_ushort4(f2bf(v.x), f2bf(v.y), f2bf(v.z), f2bf(v.w));
    ((ushort4*)dst)[lane] = u4;
#pragma unroll
    for (int off = 32; off; off >>= 1) s += __shfl_xor(s, off, 64);
    if (lane == 0) *nrm = s;
}

// ---------------- K1b: class counts ----------------
__global__ void k_count(const int* __restrict__ ys, int* __restrict__ counts,
                        int* __restrict__ qcounts) {
    int j = blockIdx.x * 256 + threadIdx.x;
    if (j < NS) {
        int c = ys[j];
        atomicAdd(&counts[c], 1);
        if (j < NQ) atomicAdd(&qcounts[c], 1);
    }
}

// ---------------- K1c: exclusive scan (tiny, serial) ----------------
__global__ void k_scan(const int* __restrict__ counts, const int* __restrict__ qcounts,
                       int* __restrict__ soff, int* __restrict__ qoff) {
    if (threadIdx.x == 0) {
        int a = 0, b = 0;
        for (int i = 0; i < NC; ++i) {
            soff[i] = a; a += counts[i];
            qoff[i] = b; b += qcounts[i];
        }
    }
}

// ---------------- K1d: scatter into class buckets ----------------
__global__ void k_scatter(const int* __restrict__ ys, const int* __restrict__ soff,
                          const int* __restrict__ qoff, int* __restrict__ scur,
                          int* __restrict__ qcur, int* __restrict__ sperm,
                          int* __restrict__ qperm) {
    int j = blockIdx.x * 256 + threadIdx.x;
    if (j < NS) {
        int c = ys[j];
        int p = atomicAdd(&scur[c], 1);
        sperm[soff[c] + p] = j;
        if (j < NQ) {
            int q = atomicAdd(&qcur[c], 1);
            qperm[qoff[c] + q] = j;
        }
    }
}

// ---------------- K1e: per-row diagonal dots: ldot[i] = xq_i . xs_i ----------------
__global__ __launch_bounds__(256) void k_diag(const float* __restrict__ xq,
                                              const float* __restrict__ xs,
                                              float* __restrict__ ldot) {
    int row = blockIdx.x * 4 + (threadIdx.x >> 6);
    int lane = threadIdx.x & 63;
    float4 a = ((const float4*)(xq + (size_t)row * DD))[lane];
    float4 b = ((const float4*)(xs + (size_t)row * DD))[lane];
    float s = a.x * b.x + a.y * b.y + a.z * b.z + a.w * b.w;
#pragma unroll
    for (int off = 32; off; off >>= 1) s += __shfl_xor(s, off, 64);
    if (lane == 0) ldot[row] = s;
}

// ---------------- K2: class centroids M_c = sum_{ys=c} xs_j, S_c = sum ns2 ------
// one block per class; output mcent layout k-major: mcent[k*64 + c]
__global__ __launch_bounds__(256) void k_cent(const float* __restrict__ xs,
                                              const float* __restrict__ ns2,
                                              const int* __restrict__ counts,
                                              const int* __restrict__ soff,
                                              const int* __restrict__ sperm,
                                              float* __restrict__ mcent,
                                              float* __restrict__ Sc) {
    __shared__ float red[4][256];
    __shared__ float sred[4];
    const int c = blockIdx.x;
    const int mc = counts[c];
    const int sbase = soff[c];
    const int tid = threadIdx.x;
    const int g = tid >> 6;     // 4 row-parallel groups
    const int lane = tid & 63;  // lane*4 = column group

    float4 acc = make_float4(0.f, 0.f, 0.f, 0.f);
    float sacc = 0.0f;
    for (int idx = g; idx < mc; idx += 4) {
        int row = sperm[sbase + idx];
        float4 v = ((const float4*)(xs + (size_t)row * DD))[lane];
        acc.x += v.x; acc.y += v.y; acc.z += v.z; acc.w += v.w;
        if (lane == 0) sacc += ns2[row];
    }
    ((float4*)red[g])[lane] = acc;
    if (lane == 0) sred[g] = sacc;
    __syncthreads();
    if (g == 0) {
        int k0 = lane * 4;
#pragma unroll
        for (int j = 0; j < 4; ++j) {
            float v = red[0][k0 + j] + red[1][k0 + j] + red[2][k0 + j] + red[3][k0 + j];
            mcent[(size_t)(k0 + j) * 64 + c] = v;
        }
        if (lane == 0) Sc[c] = sred[0] + sred[1] + sred[2] + sred[3];
    }
}

// ---------------- K3: positive logsumexp per query (per-class GEMM) ----------------
__global__ __launch_bounds__(256) void k_pos(const unsigned short* __restrict__ xqh,
                                             const unsigned short* __restrict__ xsh,
                                             const float* __restrict__ nq2,
                                             const float* __restrict__ ns2,
                                             const int* __restrict__ counts,
                                             const int* __restrict__ qcounts,
                                             const int* __restrict__ soff,
                                             const int* __restrict__ qoff,
                                             const int* __restrict__ sperm,
                                             const int* __restrict__ qperm,
                                             float* __restrict__ poslog) {
    __shared__ __align__(16) char sbuf[34816];  // union: Bsh (128x136 ushort) / Lt (64x132 f32)
    __shared__ int spsh[128];
    __shared__ float ns2sh[128];
    __shared__ int qlsh[64];
    __shared__ float nq2sh[64];

    unsigned short* Bsh = (unsigned short*)sbuf;
    float* Lt = (float*)sbuf;

    const int c = blockIdx.x;
    const int mc = counts[c];
    const int qc = qcounts[c];
    if (qc == 0) return;
    const int sbase = soff[c];
    const int qbase = qoff[c];
    const float ov = (mc > 1) ? -INFV : 0.0f;

    const int tid = threadIdx.x;
    const int lane = tid & 63;
    const int wave = tid >> 6;
    const int quad = lane >> 4;
    const int l15 = lane & 15;
    const int rowW = wave >> 1;
    const int colW = wave & 1;

    for (int q0 = blockIdx.y * 64; q0 < qc; q0 += 128) {
        __syncthreads();
        if (tid < 64) {
            int idx = q0 + tid;
            int qi = (idx < qc) ? qperm[qbase + idx] : -1;
            qlsh[tid] = qi;
            nq2sh[tid] = (qi >= 0) ? nq2[qi] : 0.0f;
        }
        __syncthreads();

        bf16x8 afr[2][8];
#pragma unroll
        for (int m = 0; m < 2; ++m) {
            int rl = rowW * 32 + m * 16 + l15;
            int qi = qlsh[rl];
            int qiL = qi < 0 ? 0 : qi;
            const unsigned short* ap = xqh + (size_t)qiL * DD + quad * 8;
#pragma unroll
            for (int kk = 0; kk < 8; ++kk) afr[m][kk] = *(const bf16x8*)(ap + kk * 32);
        }
        float nqr[2][4];
        int qid[2][4];
#pragma unroll
        for (int m = 0; m < 2; ++m)
#pragma unroll
            for (int r = 0; r < 4; ++r) {
                int rl = rowW * 32 + m * 16 + quad * 4 + r;
                qid[m][r] = qlsh[rl];
                nqr[m][r] = nq2sh[rl];
            }

        float mrun[16], srun[16];
#pragma unroll
        for (int i = 0; i < 16; ++i) { mrun[i] = -1e30f; srun[i] = 0.0f; }

        floatx4 acc[2][4];
#pragma unroll
        for (int m = 0; m < 2; ++m)
#pragma unroll
            for (int n = 0; n < 4; ++n) acc[m][n] = (floatx4)0.0f;

        for (int j0 = 0; j0 < mc; j0 += 128) {
            __syncthreads();
            if (tid < 128) {
                int idx = j0 + tid;
                int sj = (idx < mc) ? sperm[sbase + idx] : -1;
                spsh[tid] = sj;
                ns2sh[tid] = (sj >= 0) ? ns2[sj] : 0.0f;
            }
            __syncthreads();
#pragma unroll
            for (int kh = 0; kh < 2; ++kh) {
#pragma unroll
                for (int it = 0; it < 8; ++it) {
                    int ch = it * 256 + tid;
                    int row = ch >> 4, u = ch & 15;
                    int sj = spsh[row];
                    int sjL = sj < 0 ? 0 : sj;
                    *(uint4v*)(&Bsh[row * 136 + u * 8]) =
                        *(const uint4v*)(xsh + (size_t)sjL * DD + kh * 128 + u * 8);
                }
                __syncthreads();
#pragma unroll
                for (int k = 0; k < 4; ++k) {
                    bf16x8 bfr[4];
#pragma unroll
                    for (int n = 0; n < 4; ++n) {
                        int colc = colW * 64 + n * 16 + l15;
                        bfr[n] = *(const bf16x8*)(&Bsh[colc * 136 + k * 32 + quad * 8]);
                    }
#pragma unroll
                    for (int m = 0; m < 2; ++m)
#pragma unroll
                        for (int n = 0; n < 4; ++n)
                            acc[m][n] = __builtin_amdgcn_mfma_f32_16x16x32_bf16(
                                afr[m][kh * 4 + k], bfr[n], acc[m][n], 0, 0, 0);
                }
                __syncthreads();
            }
            // write logits to Lt (reuses Bsh memory; safe after sync)
#pragma unroll
            for (int n = 0; n < 4; ++n) {
                int colc = colW * 64 + n * 16 + l15;
                bool cval = (j0 + colc) < mc;
                int sj = spsh[colc];
                float nsc = ns2sh[colc];
#pragma unroll
                for (int m = 0; m < 2; ++m) {
                    int rbase = rowW * 32 + m * 16 + quad * 4;
#pragma unroll
                    for (int r = 0; r < 4; ++r) {
                        float logit = fminf(acc[m][n][r] - 0.5f * (nqr[m][r] + nsc), 0.0f);
                        if (sj == qid[m][r]) logit = ov;  // diagonal override
                        if (!cval) logit = -1e30f;
                        Lt[(rbase + r) * 132 + colc] = logit;
                    }
                    acc[m][n] = (floatx4)0.0f;
                }
            }
            __syncthreads();
            // per-row online merge; wave owns rows wave*16..+15
#pragma unroll
            for (int rr = 0; rr < 16; ++rr) {
                int rl = wave * 16 + rr;
                float v0 = Lt[rl * 132 + lane];
                float v1 = Lt[rl * 132 + 64 + lane];
                float mt = fmaxf(v0, v1);
#pragma unroll
                for (int off = 32; off; off >>= 1) mt = fmaxf(mt, __shfl_xor(mt, off, 64));
                float e = __expf(v0 - mt) + __expf(v1 - mt);
#pragma unroll
                for (int off = 32; off; off >>= 1) e += __shfl_xor(e, off, 64);
                float mn = fmaxf(mrun[rr], mt);
                srun[rr] = srun[rr] * __expf(mrun[rr] - mn) + e * __expf(mt - mn);
                mrun[rr] = mn;
            }
        }
#pragma unroll
        for (int rr = 0; rr < 16; ++rr) {
            int rl = wave * 16 + rr;
            int qi = qlsh[rl];
            if (qi >= 0 && lane == 0) poslog[qi] = mrun[rr] + __logf(srun[rr]);
        }
    }
}

// ---------------- K4: summed via centroids + finalize ----------------
// block = 4 rows; lane = class. summed[i][c] = xq_i.M_c - 0.5*cnt_c*nq_i - 0.5*S_c
__global__ __launch_bounds__(256) void k_final(const float* __restrict__ xq,
                                               const float* __restrict__ mcent,
                                               const float* __restrict__ Sc,
                                               const int* __restrict__ counts,
                                               const int* __restrict__ yq,
                                               const float* __restrict__ nq2,
                                               const float* __restrict__ ns2,
                                               const float* __restrict__ ldot,
                                               const float* __restrict__ poslog,
                                               float* __restrict__ out) {
    __shared__ float Mt_sh[128 * 64];  // 32 KB, half of K at a time
    __shared__ float xq_sh[4][256];
    __shared__ float sc_sh[64];
    __shared__ int cnt_sh[64];

    const int tid = threadIdx.x;
    const int wave = tid >> 6;  // row within block
    const int lane = tid & 63;  // class
    const int row = blockIdx.x * 4 + wave;

    {   // stage 4 xq rows (coalesced float4)
        int fi = tid * 4;
        float4 v = *(const float4*)(xq + (size_t)blockIdx.x * 4 * DD + fi);
        *(float4*)(&xq_sh[fi >> 8][fi & 255]) = v;
    }
    if (tid < 64) { sc_sh[tid] = Sc[tid]; cnt_sh[tid] = counts[tid]; }

    float acc = 0.0f;
#pragma unroll
    for (int half = 0; half < 2; ++half) {
        __syncthreads();
#pragma unroll
        for (int i = 0; i < 8; ++i) {
            int fi = i * 1024 + tid * 4;
            *(float4*)(&Mt_sh[fi]) = *(const float4*)(mcent + half * 8192 + fi);
        }
        __syncthreads();
#pragma unroll 4
        for (int k = 0; k < 128; ++k)
            acc += xq_sh[wave][half * 128 + k] * Mt_sh[k * 64 + lane];
    }

    const int y = yq[row];
    const int cnt = cnt_sh[lane];
    const float nqv = nq2[row];
    float val = acc - 0.5f * (float)cnt * nqv - 0.5f * sc_sh[lane];
    if (lane == y) {
        float lii = ldot[row] - 0.5f * (nqv + ns2[row]);  // linear diag logit
        float ov = (cnt > 1) ? -INFV : 0.0f;
        val += ov - lii;
    }
    float adj = (float)(cnt - (lane == y ? 1 : 0));
    float v = val / adj;
    float m = v;
#pragma unroll
    for (int off = 32; off; off >>= 1) m = fmaxf(m, __shfl_xor(m, off, 64));
    float e = __expf(v - m);
#pragma unroll
    for (int off = 32; off; off >>= 1) e += __shfl_xor(e, off, 64);
    if (lane == 0) {
        float neg = m + __logf(e);
        atomicAdd(out, (neg - poslog[row]) * (1.0f / (float)NQ));
    }
}

extern "C" void kernel_launch(void* const* d_in, const int* in_sizes, int n_in,
                              void* d_out, int out_size, void* d_ws, size_t ws_size,
                              hipStream_t stream) {
    const float* xq = (const float*)d_in[0];
    const int* yq = (const int*)d_in[1];
    const float* xs = (const float*)d_in[2];
    const int* ys = (const int*)d_in[3];
    float* out = (float*)d_out;
    char* ws = (char*)d_ws;

    unsigned short* xqh = (unsigned short*)(ws + 0);        // 2 MB
    unsigned short* xsh = (unsigned short*)(ws + 2097152);  // 4 MB
    float* nq2 = (float*)(ws + 6291456);                    // 16 KB
    float* ns2 = (float*)(ws + 6307840);                    // 32 KB
    int* counts = (int*)(ws + 6340608);
    int* qcounts = (int*)(ws + 6340864);
    int* soff = (int*)(ws + 6341120);
    int* qoff = (int*)(ws + 6341376);
    int* scur = (int*)(ws + 6341632);
    int* qcur = (int*)(ws + 6341888);
    int* sperm = (int*)(ws + 6342144);   // 32 KB
    int* qperm = (int*)(ws + 6374912);   // 16 KB
    float* poslog = (float*)(ws + 6391296);  // 16 KB
    float* mcent = (float*)(ws + 6407680);   // 64 KB  [k*64+c]
    float* Sc = (float*)(ws + 6473216);      // 256 B
    float* ldot = (float*)(ws + 6473472);    // 16 KB

    hipMemsetAsync(ws + 6340608, 0, 1536, stream);  // counts..qcur
    hipMemsetAsync(d_out, 0, (size_t)out_size * 4, stream);

    k_prep<<<dim3((NQ + NS) / 4), dim3(256), 0, stream>>>(xq, xs, xqh, xsh, nq2, ns2);
    k_count<<<dim3(NS / 256), dim3(256), 0, stream>>>(ys, counts, qcounts);
    k_scan<<<dim3(1), dim3(64), 0, stream>>>(counts, qcounts, soff, qoff);
    k_diag<<<dim3(NQ / 4), dim3(256), 0, stream>>>(xq, xs, ldot);
    k_scatter<<<dim3(NS / 256), dim3(256), 0, stream>>>(ys, soff, qoff, scur, qcur,
                                                        sperm, qperm);
    k_cent<<<dim3(NC), dim3(256), 0, stream>>>(xs, ns2, counts, soff, sperm, mcent, Sc);
    k_pos<<<dim3(NC, 2), dim3(256), 0, stream>>>(xqh, xsh, nq2, ns2, counts, qcounts,
                                                 soff, qoff, sperm, qperm, poslog);
    k_final<<<dim3(NQ / 4), dim3(256), 0, stream>>>(xq, mcent, Sc, counts, yq, nq2, ns2,
                                                    ldot, poslog, out);
}

// Round 3
// 117.126 us; speedup vs baseline: 3.4209x; 1.8785x over previous
//
#include <hip/hip_runtime.h>

#define NQ 4096
#define NS 8192
#define DD 256
#define NC 64
#define INFV 1000.0f

typedef __attribute__((ext_vector_type(8))) __bf16 bf16x8;
typedef __attribute__((ext_vector_type(4))) float floatx4;

__device__ inline unsigned short f2bf(float f) {
    unsigned int u = __builtin_bit_cast(unsigned int, f);
    unsigned int r = (u + 0x7FFFu + ((u >> 16) & 1u)) >> 16;
    return (unsigned short)r;
}

__device__ inline bf16x8 cvt8(const float* p) {
    bf16x8 o;
    unsigned short tmp[8];
#pragma unroll
    for (int i = 0; i < 8; ++i) tmp[i] = f2bf(p[i]);
    return *(bf16x8*)tmp;
}

// ---------------- K1a: convert to bf16 + row squared norms ----------------
__global__ __launch_bounds__(256) void k_prep(const float* __restrict__ xq,
                                              const float* __restrict__ xs,
                                              unsigned short* __restrict__ xqh,
                                              unsigned short* __restrict__ xsh,
                                              float* __restrict__ nq2,
                                              float* __restrict__ ns2) {
    int row = blockIdx.x * 4 + (threadIdx.x >> 6);
    int lane = threadIdx.x & 63;
    const float* src;
    unsigned short* dst;
    float* nrm;
    if (row < NQ) {
        src = xq + (size_t)row * DD; dst = xqh + (size_t)row * DD; nrm = nq2 + row;
    } else {
        int r = row - NQ;
        src = xs + (size_t)r * DD; dst = xsh + (size_t)r * DD; nrm = ns2 + r;
    }
    float4 v = ((const float4*)src)[lane];
    float s = v.x * v.x + v.y * v.y + v.z * v.z + v.w * v.w;
    ushort4 u4 = make_ushort4(f2bf(v.x), f2bf(v.y), f2bf(v.z), f2bf(v.w));
    ((ushort4*)dst)[lane] = u4;
#pragma unroll
    for (int off = 32; off; off >>= 1) s += __shfl_xor(s, off, 64);
    if (lane == 0) *nrm = s;
}

// ---------------- K1b: fused count + scan + scatter (single block) ----------------
__global__ __launch_bounds__(1024) void k_hist(const int* __restrict__ ys,
                                               int* __restrict__ counts,
                                               int* __restrict__ qcounts,
                                               int* __restrict__ soff,
                                               int* __restrict__ qoff,
                                               int* __restrict__ sperm,
                                               int* __restrict__ qperm) {
    __shared__ int h[NC], hq[NC], cur[NC], curq[NC];
    const int tid = threadIdx.x;
    if (tid < NC) { h[tid] = 0; hq[tid] = 0; }
    __syncthreads();
    int v[8];
#pragma unroll
    for (int i = 0; i < 8; ++i) {
        int j = tid + i * 1024;
        v[i] = ys[j];
        atomicAdd(&h[v[i]], 1);
        if (j < NQ) atomicAdd(&hq[v[i]], 1);
    }
    __syncthreads();
    if (tid < NC) {
        int cv = h[tid], qv = hq[tid];
        counts[tid] = cv; qcounts[tid] = qv;
        int x = cv, xb = qv;
#pragma unroll
        for (int off = 1; off < 64; off <<= 1) {
            int y0 = __shfl_up(x, off, 64);
            int y1 = __shfl_up(xb, off, 64);
            if (tid >= off) { x += y0; xb += y1; }
        }
        soff[tid] = x - cv; qoff[tid] = xb - qv;
        cur[tid] = x - cv; curq[tid] = xb - qv;
    }
    __syncthreads();
#pragma unroll
    for (int i = 0; i < 8; ++i) {
        int j = tid + i * 1024;
        int c = v[i];
        int p = atomicAdd(&cur[c], 1);
        sperm[p] = j;
        if (j < NQ) {
            int q = atomicAdd(&curq[c], 1);
            qperm[q] = j;
        }
    }
}

// ---------------- K1e: per-row diagonal dots: ldot[i] = xq_i . xs_i ----------------
__global__ __launch_bounds__(256) void k_diag(const float* __restrict__ xq,
                                              const float* __restrict__ xs,
                                              float* __restrict__ ldot) {
    int row = blockIdx.x * 4 + (threadIdx.x >> 6);
    int lane = threadIdx.x & 63;
    float4 a = ((const float4*)(xq + (size_t)row * DD))[lane];
    float4 b = ((const float4*)(xs + (size_t)row * DD))[lane];
    float s = a.x * b.x + a.y * b.y + a.z * b.z + a.w * b.w;
#pragma unroll
    for (int off = 32; off; off >>= 1) s += __shfl_xor(s, off, 64);
    if (lane == 0) ldot[row] = s;
}

// ---------------- K2: class centroids (c-major fp32, atomic partials) ----------------
__global__ __launch_bounds__(256) void k_cent(const float* __restrict__ xs,
                                              const float* __restrict__ ns2,
                                              const int* __restrict__ counts,
                                              const int* __restrict__ soff,
                                              const int* __restrict__ sperm,
                                              float* __restrict__ mcent,
                                              float* __restrict__ Sc) {
    __shared__ float red[4][256];
    __shared__ float sred[4];
    const int c = blockIdx.x;
    const int yb = blockIdx.y;
    const int mc = counts[c];
    const int sbase = soff[c];
    const int tid = threadIdx.x;
    const int g = tid >> 6;
    const int lane = tid & 63;

    float4 acc = make_float4(0.f, 0.f, 0.f, 0.f);
    float sacc = 0.0f;
    for (int idx = yb * 4 + g; idx < mc; idx += 16) {
        int row = sperm[sbase + idx];
        float4 v = ((const float4*)(xs + (size_t)row * DD))[lane];
        acc.x += v.x; acc.y += v.y; acc.z += v.z; acc.w += v.w;
        if (lane == 0) sacc += ns2[row];
    }
    ((float4*)red[g])[lane] = acc;
    if (lane == 0) sred[g] = sacc;
    __syncthreads();
    if (g == 0) {
        int k0 = lane * 4;
#pragma unroll
        for (int j = 0; j < 4; ++j) {
            float v = red[0][k0 + j] + red[1][k0 + j] + red[2][k0 + j] + red[3][k0 + j];
            atomicAdd(&mcent[(size_t)c * DD + k0 + j], v);
        }
        if (lane == 0) atomicAdd(&Sc[c], sred[0] + sred[1] + sred[2] + sred[3]);
    }
}

// ---------------- K3: positive logsumexp (class c, 16-query tile per block) ------
// 4 waves split the support range; each wave: one 16x16 MFMA tile per 16-col step,
// B frags gathered directly from global via sperm. Per-lane online (m,s), then
// 16-lane shfl merge + cross-wave LDS merge.
__global__ __launch_bounds__(256) void k_pos(const unsigned short* __restrict__ xqh,
                                             const unsigned short* __restrict__ xsh,
                                             const float* __restrict__ nq2,
                                             const float* __restrict__ ns2,
                                             const int* __restrict__ counts,
                                             const int* __restrict__ qcounts,
                                             const int* __restrict__ soff,
                                             const int* __restrict__ qoff,
                                             const int* __restrict__ sperm,
                                             const int* __restrict__ qperm,
                                             float* __restrict__ poslog) {
    __shared__ int qish[16];
    __shared__ float nqsh[16];
    __shared__ float msh[4][16], ssh[4][16];

    const int c = blockIdx.x;
    const int qc = qcounts[c];
    const int mc = counts[c];
    const int sbase = soff[c];
    const int qbase = qoff[c];
    const float ov = (mc > 1) ? -INFV : 0.0f;

    const int tid = threadIdx.x;
    const int lane = tid & 63;
    const int wave = tid >> 6;
    const int quad = lane >> 4;
    const int l15 = lane & 15;

    for (int q0 = blockIdx.y * 16; q0 < qc; q0 += gridDim.y * 16) {
        __syncthreads();
        if (tid < 16) {
            int idx = q0 + tid;
            int qi = (idx < qc) ? qperm[qbase + idx] : -1;
            qish[tid] = qi;
            nqsh[tid] = (qi >= 0) ? nq2[qi] : 0.0f;
        }
        __syncthreads();

        // A frags: row = query l15, k = ks*32 + quad*8
        int qrow = qish[l15];
        int qrowL = qrow < 0 ? 0 : qrow;
        const unsigned short* ap = xqh + (size_t)qrowL * DD + quad * 8;
        bf16x8 afr[8];
#pragma unroll
        for (int ks = 0; ks < 8; ++ks) afr[ks] = *(const bf16x8*)(ap + ks * 32);

        int qid[4];
        float nqr[4];
#pragma unroll
        for (int r = 0; r < 4; ++r) {
            qid[r] = qish[quad * 4 + r];
            nqr[r] = nqsh[quad * 4 + r];
        }

        float mrun[4], srun[4];
#pragma unroll
        for (int r = 0; r < 4; ++r) { mrun[r] = -1e30f; srun[r] = 0.0f; }

        for (int jt = wave * 16; jt < mc; jt += 64) {
            int jcol = jt + l15;
            bool valid = jcol < mc;
            int sj = valid ? sperm[sbase + jcol] : -1;
            int sjL = sj < 0 ? 0 : sj;
            float nsv = valid ? ns2[sjL] : 0.0f;
            const unsigned short* bp = xsh + (size_t)sjL * DD + quad * 8;
            floatx4 acc = (floatx4)0.0f;
#pragma unroll
            for (int ks = 0; ks < 8; ++ks) {
                bf16x8 bfr = *(const bf16x8*)(bp + ks * 32);
                acc = __builtin_amdgcn_mfma_f32_16x16x32_bf16(afr[ks], bfr, acc, 0, 0, 0);
            }
            if (valid) {
#pragma unroll
                for (int r = 0; r < 4; ++r) {
                    float v = fminf(acc[r] - 0.5f * (nqr[r] + nsv), 0.0f);
                    if (sj == qid[r]) v = ov;
                    float mn = fmaxf(mrun[r], v);
                    srun[r] = srun[r] * __expf(mrun[r] - mn) + __expf(v - mn);
                    mrun[r] = mn;
                }
            }
        }
        // merge across the 16 lanes of each quad
#pragma unroll
        for (int r = 0; r < 4; ++r) {
#pragma unroll
            for (int off = 1; off < 16; off <<= 1) {
                float m2 = __shfl_xor(mrun[r], off, 64);
                float s2 = __shfl_xor(srun[r], off, 64);
                float mn = fmaxf(mrun[r], m2);
                srun[r] = srun[r] * __expf(mrun[r] - mn) + s2 * __expf(m2 - mn);
                mrun[r] = mn;
            }
            if (l15 == 0) {
                msh[wave][quad * 4 + r] = mrun[r];
                ssh[wave][quad * 4 + r] = srun[r];
            }
        }
        __syncthreads();
        if (tid < 16) {
            int qi = qish[tid];
            if (qi >= 0) {
                float m = -1e30f, s = 0.0f;
#pragma unroll
                for (int w = 0; w < 4; ++w) {
                    float mw = msh[w][tid], sw = ssh[w][tid];
                    float mn = fmaxf(m, mw);
                    s = s * __expf(m - mn) + sw * __expf(mw - mn);
                    m = mn;
                }
                poslog[qi] = m + __logf(s);
            }
        }
    }
}

// ---------------- K4: summed via centroid MFMA + finalize ----------------
// 64 blocks x 64 rows; wave = 16-row tile, 4 n-tiles cover 64 classes.
__global__ __launch_bounds__(256) void k_final(const unsigned short* __restrict__ xqh,
                                               const float* __restrict__ mcent,
                                               const float* __restrict__ Sc,
                                               const int* __restrict__ counts,
                                               const int* __restrict__ yq,
                                               const float* __restrict__ nq2,
                                               const float* __restrict__ ns2,
                                               const float* __restrict__ ldot,
                                               const float* __restrict__ poslog,
                                               float* __restrict__ out) {
    __shared__ float cntf[64], scs[64], nqs[64], ldts[64], ns2s[64], pls[64], red[64];
    __shared__ int ysh[64];

    const int b = blockIdx.x;
    const int tid = threadIdx.x;
    const int lane = tid & 63;
    const int wave = tid >> 6;
    const int quad = lane >> 4;
    const int l15 = lane & 15;

    if (tid < 64) {
        cntf[tid] = (float)counts[tid];
        scs[tid] = Sc[tid];
        int row = b * 64 + tid;
        nqs[tid] = nq2[row];
        ysh[tid] = yq[row];
        ldts[tid] = ldot[row];
        ns2s[tid] = ns2[row];
        pls[tid] = poslog[row];
    }
    __syncthreads();

    // A frags: row = b*64 + wave*16 + l15
    const unsigned short* ap = xqh + (size_t)(b * 64 + wave * 16 + l15) * DD + quad * 8;
    bf16x8 afr[8];
#pragma unroll
    for (int ks = 0; ks < 8; ++ks) afr[ks] = *(const bf16x8*)(ap + ks * 32);

    floatx4 acc[4];
#pragma unroll
    for (int n = 0; n < 4; ++n) acc[n] = (floatx4)0.0f;

#pragma unroll
    for (int n = 0; n < 4; ++n) {
        const float* bp = mcent + (size_t)(n * 16 + l15) * DD + quad * 8;
#pragma unroll
        for (int ks = 0; ks < 8; ++ks) {
            bf16x8 bfr = cvt8(bp + ks * 32);
            acc[n] = __builtin_amdgcn_mfma_f32_16x16x32_bf16(afr[ks], bfr, acc[n], 0, 0, 0);
        }
    }

    // epilogue: per-row logsumexp over 64 classes
#pragma unroll
    for (int r = 0; r < 4; ++r) {
        int rl = wave * 16 + quad * 4 + r;
        float nqv = nqs[rl];
        int y = ysh[rl];
        float vv[4];
#pragma unroll
        for (int n = 0; n < 4; ++n) {
            int col = n * 16 + l15;
            float cnt = cntf[col];
            float val = acc[n][r] - 0.5f * cnt * nqv - 0.5f * scs[col];
            float sub = (col == y) ? 1.0f : 0.0f;
            if (col == y) {
                float lii = ldts[rl] - 0.5f * (nqv + ns2s[rl]);
                val += ((cnt > 1.5f) ? -INFV : 0.0f) - lii;
            }
            vv[n] = val / (cnt - sub);
        }
        float m = fmaxf(fmaxf(vv[0], vv[1]), fmaxf(vv[2], vv[3]));
#pragma unroll
        for (int off = 1; off < 16; off <<= 1) m = fmaxf(m, __shfl_xor(m, off, 64));
        float e = __expf(vv[0] - m) + __expf(vv[1] - m) + __expf(vv[2] - m) +
                  __expf(vv[3] - m);
#pragma unroll
        for (int off = 1; off < 16; off <<= 1) e += __shfl_xor(e, off, 64);
        if (l15 == 0) red[rl] = (m + __logf(e) - pls[rl]) * (1.0f / (float)NQ);
    }
    __syncthreads();
    if (tid < 64) {
        float s = red[tid];
#pragma unroll
        for (int off = 32; off; off >>= 1) s += __shfl_xor(s, off, 64);
        if (tid == 0) atomicAdd(out, s);
    }
}

extern "C" void kernel_launch(void* const* d_in, const int* in_sizes, int n_in,
                              void* d_out, int out_size, void* d_ws, size_t ws_size,
                              hipStream_t stream) {
    const float* xq = (const float*)d_in[0];
    const int* yq = (const int*)d_in[1];
    const float* xs = (const float*)d_in[2];
    const int* ys = (const int*)d_in[3];
    float* out = (float*)d_out;
    char* ws = (char*)d_ws;

    unsigned short* xqh = (unsigned short*)(ws + 0);        // 2 MB
    unsigned short* xsh = (unsigned short*)(ws + 2097152);  // 4 MB -> ends 6291456
    float* nq2 = (float*)(ws + 6291456);     // 16 KB
    float* ns2 = (float*)(ws + 6307840);     // 32 KB
    int* counts = (int*)(ws + 6340608);      // 256 B
    int* qcounts = (int*)(ws + 6340864);
    int* soff = (int*)(ws + 6341120);
    int* qoff = (int*)(ws + 6341376);
    int* sperm = (int*)(ws + 6341632);       // 32 KB
    int* qperm = (int*)(ws + 6374400);       // 16 KB
    float* poslog = (float*)(ws + 6390784);  // 16 KB
    float* ldot = (float*)(ws + 6407168);    // 16 KB
    float* mcent = (float*)(ws + 6423552);   // 64 KB fp32, c-major [c*256+k]
    float* Sc = (float*)(ws + 6489088);      // 256 B

    hipMemsetAsync(ws + 6423552, 0, 65792, stream);  // mcent + Sc
    hipMemsetAsync(d_out, 0, (size_t)out_size * 4, stream);

    k_prep<<<dim3((NQ + NS) / 4), dim3(256), 0, stream>>>(xq, xs, xqh, xsh, nq2, ns2);
    k_hist<<<dim3(1), dim3(1024), 0, stream>>>(ys, counts, qcounts, soff, qoff, sperm,
                                               qperm);
    k_diag<<<dim3(NQ / 4), dim3(256), 0, stream>>>(xq, xs, ldot);
    k_cent<<<dim3(NC, 4), dim3(256), 0, stream>>>(xs, ns2, counts, soff, sperm, mcent,
                                                  Sc);
    k_pos<<<dim3(NC, 8), dim3(256), 0, stream>>>(xqh, xsh, nq2, ns2, counts, qcounts,
                                                 soff, qoff, sperm, qperm, poslog);
    k_final<<<dim3(64), dim3(256), 0, stream>>>(xqh, mcent, Sc, counts, yq, nq2, ns2,
                                                ldot, poslog, out);
}